// Round 1
// baseline (3169.765 us; speedup 1.0000x reference)
//
#include <hip/hip_runtime.h>
#include <hip/hip_bf16.h>

#define DIM 128
#define K 8
#define EPS 1e-8f
#define SQRT_EPS 1e-6f

// ---------------- MLP: logits = relu(x@W1+b1)@W2+b2, plus sign mask ----------
__global__ __launch_bounds__(128) void mlp_kernel(
    const float* __restrict__ x, const float* __restrict__ W1,
    const float* __restrict__ b1, const float* __restrict__ W2,
    const float* __restrict__ b2, float* __restrict__ logits,
    unsigned* __restrict__ sgn, int n_vars)
{
    __shared__ float xs[8][DIM];
    __shared__ float hs[8][DIM];
    const int row0 = blockIdx.x * 8;
    const int t = threadIdx.x;  // 0..127

    #pragma unroll
    for (int r = 0; r < 8; ++r) {
        int row = row0 + r;
        xs[r][t] = (row < n_vars) ? x[(size_t)row * DIM + t] : 0.f;
    }
    __syncthreads();

    float acc[8];
    float bias = b1[t];
    #pragma unroll
    for (int r = 0; r < 8; ++r) acc[r] = bias;

    for (int i = 0; i < DIM; ++i) {
        float w = W1[i * DIM + t];
        #pragma unroll
        for (int r = 0; r < 8; ++r) acc[r] = fmaf(xs[r][i], w, acc[r]);
    }
    #pragma unroll
    for (int r = 0; r < 8; ++r) hs[r][t] = fmaxf(acc[r], 0.f);
    __syncthreads();

    // Second layer: 64 outputs (8 rows x 8 k) on wave 0.
    if (t < 64) {
        int r = t >> 3, kk = t & 7;
        float s = b2[kk];
        for (int j = 0; j < DIM; ++j) s = fmaf(hs[r][j], W2[j * K + kk], s);
        unsigned long long bal = __ballot(s > 0.f);
        int row = row0 + r;
        if (row < n_vars) {
            logits[(size_t)row * K + kk] = s;
            if (kk == 0) sgn[row] = (unsigned)((bal >> (r * 8)) & 0xFFull);
        }
    }
}

// ---------------- Edge gather + softplus scatter + hard-mask scatter ---------
__global__ __launch_bounds__(256) void edge_kernel(
    const float* __restrict__ logits, const unsigned* __restrict__ sgn,
    const float* __restrict__ pol, const int* __restrict__ vi,
    const int* __restrict__ ci, float* __restrict__ clause_sum,
    unsigned* __restrict__ clause_mask, int n_edges)
{
    int e = blockIdx.x * 256 + threadIdx.x;
    if (e >= n_edges) return;
    int v = vi[e];
    int c = ci[e];
    float p = pol[e];

    const float4* lp = (const float4*)(logits + (size_t)v * K);
    float4 l0 = lp[0], l1 = lp[1];
    float l[K] = {l0.x, l0.y, l0.z, l0.w, l1.x, l1.y, l1.z, l1.w};

    #pragma unroll
    for (int j = 0; j < K; ++j) {
        float lit = l[j] * p;
        // stable softplus: max(x,0) + log(1+exp(-|x|))
        float sp = fmaxf(lit, 0.f) + __logf(1.f + __expf(-fabsf(lit)));
        atomicAdd(&clause_sum[(size_t)c * K + j], sp);
    }

    unsigned m = sgn[v];
    unsigned em = (p > 0.f) ? m : (~m & 0xFFu);
    atomicOr(&clause_mask[c], em | 0x100u);
}

// ---------------- Per-graph reduction, sort, cost dot, solved ----------------
__global__ __launch_bounds__(256) void graph_kernel(
    const float* __restrict__ clause_sum, const unsigned* __restrict__ clause_mask,
    const int* __restrict__ clause_batch, int n_clauses, float* __restrict__ out)
{
    const int g = blockIdx.x;
    __shared__ int s_lo, s_hi;
    if (threadIdx.x == 0) {
        int lo = 0, hi = n_clauses;
        while (lo < hi) { int mid = (lo + hi) >> 1; if (clause_batch[mid] < g) lo = mid + 1; else hi = mid; }
        s_lo = lo;
        int lo2 = lo, hi2 = n_clauses;
        while (lo2 < hi2) { int mid = (lo2 + hi2) >> 1; if (clause_batch[mid] <= g) lo2 = mid + 1; else hi2 = mid; }
        s_hi = lo2;
    }
    __syncthreads();
    const int lo = s_lo, hi = s_hi;
    const int t = threadIdx.x;
    const int kk = t & 7, cidx = t >> 3;  // 32 clause-lanes x 8 k-lanes

    float acc = 0.f;
    for (int c = lo + cidx; c < hi; c += 32) {
        float s = clause_sum[(size_t)c * K + kk];
        float cv = __expf(-s);
        acc += cv * (-__logf(1.f - cv + EPS));
    }

    unsigned mk = 0xFFu;
    for (int c = lo + t; c < hi; c += 256) {
        unsigned cm = clause_mask[c];
        mk &= (cm & 0x100u) ? (cm & 0xFFu) : 0u;
    }

    __shared__ float red[256];
    __shared__ unsigned redm[256];
    red[t] = acc;
    redm[t] = mk;
    __syncthreads();

    // AND-reduce mask over all 256 threads
    for (int s = 128; s >= 1; s >>= 1) {
        if (t < s) redm[t] &= redm[t + s];
        __syncthreads();
    }
    // sum-reduce loss over the 32 clause-lanes (stride 8 in t)
    for (int sc = 16; sc >= 1; sc >>= 1) {
        if (cidx < sc && kk == (t & 7)) red[t] += red[t + sc * 8];
        __syncthreads();
    }

    __shared__ float pgl[K];
    if (t < K) {
        pgl[t] = sqrtf(red[t] + SQRT_EPS) - sqrtf(SQRT_EPS);
    }
    __syncthreads();

    if (t == 0) {
        float v[K];
        #pragma unroll
        for (int i = 0; i < K; ++i) v[i] = pgl[i];
        // insertion sort descending
        #pragma unroll
        for (int i = 1; i < K; ++i) {
            float key = v[i];
            int j = i - 1;
            while (j >= 0 && v[j] < key) { v[j + 1] = v[j]; --j; }
            v[j + 1] = key;
        }
        float dot = 0.f;
        #pragma unroll
        for (int i = 0; i < K; ++i) {
            float cst = (float)((i + 1) * (i + 1));
            dot = fmaf(v[i], cst, dot);
        }
        atomicAdd(&out[0], dot * (1.f / 204.f));
        out[1 + g] = (redm[0] != 0u) ? 1.f : 0.f;
    }
}

// ---------------------------------------------------------------------------
extern "C" void kernel_launch(void* const* d_in, const int* in_sizes, int n_in,
                              void* d_out, int out_size, void* d_ws, size_t ws_size,
                              hipStream_t stream) {
    const float* x   = (const float*)d_in[0];
    const float* pol = (const float*)d_in[1];
    const int* vi    = (const int*)d_in[2];
    const int* ci    = (const int*)d_in[3];
    const int* cb    = (const int*)d_in[4];
    const float* W1  = (const float*)d_in[5];
    const float* b1  = (const float*)d_in[6];
    const float* W2  = (const float*)d_in[7];
    const float* b2  = (const float*)d_in[8];

    const int n_vars    = in_sizes[0] / DIM;
    const int n_edges   = in_sizes[1];
    const int n_clauses = in_sizes[4];
    const int n_graphs  = out_size - 1;

    char* ws = (char*)d_ws;
    float*    logits      = (float*)ws;                                   // n_vars*8*4   = 16,000,000
    unsigned* sgn         = (unsigned*)(ws + (size_t)n_vars * K * 4);     // n_vars*4     =  2,000,000
    char*     zbase       = ws + (size_t)n_vars * K * 4 + (size_t)n_vars * 4;
    float*    clause_sum  = (float*)zbase;                                // n_clauses*8*4 = 64,000,000
    unsigned* clause_mask = (unsigned*)(zbase + (size_t)n_clauses * K * 4); // n_clauses*4 = 8,000,000

    // zero the scatter targets and output accumulator (graph-capture safe)
    hipMemsetAsync(zbase, 0, (size_t)n_clauses * K * 4 + (size_t)n_clauses * 4, stream);
    hipMemsetAsync(d_out, 0, (size_t)out_size * 4, stream);

    mlp_kernel<<<(n_vars + 7) / 8, 128, 0, stream>>>(x, W1, b1, W2, b2, logits, sgn, n_vars);
    edge_kernel<<<(n_edges + 255) / 256, 256, 0, stream>>>(logits, sgn, pol, vi, ci,
                                                           clause_sum, clause_mask, n_edges);
    graph_kernel<<<n_graphs, 256, 0, stream>>>(clause_sum, clause_mask, cb, n_clauses,
                                               (float*)d_out);
}

// Round 2
// 864.040 us; speedup vs baseline: 3.6685x; 3.6685x over previous
//
#include <hip/hip_runtime.h>
#include <hip/hip_bf16.h>

#define DIM 128
#define K 8
#define EPS 1e-8f
#define SQRT_EPS 1e-6f

#define CB 1024          // clauses per bucket
#define CSHIFT 10
#define NBMAX 2048       // max buckets (n_clauses/CB = 1954 here)
#define SBLK 1024        // partition blocks
#define MAXSLOT 32       // graph slots per bucket

// ---------------- MLP: logits = relu(x@W1+b1)@W2+b2 -------------------------
__global__ __launch_bounds__(128) void mlp_kernel(
    const float* __restrict__ x, const float* __restrict__ W1,
    const float* __restrict__ b1, const float* __restrict__ W2,
    const float* __restrict__ b2, float* __restrict__ logits, int n_vars)
{
    __shared__ float xs[8][DIM];
    __shared__ float hs[8][DIM];
    const int row0 = blockIdx.x * 8;
    const int t = threadIdx.x;  // 0..127

    #pragma unroll
    for (int r = 0; r < 8; ++r) {
        int row = row0 + r;
        xs[r][t] = (row < n_vars) ? x[(size_t)row * DIM + t] : 0.f;
    }
    __syncthreads();

    float acc[8];
    float bias = b1[t];
    #pragma unroll
    for (int r = 0; r < 8; ++r) acc[r] = bias;

    for (int i = 0; i < DIM; ++i) {
        float w = W1[i * DIM + t];
        #pragma unroll
        for (int r = 0; r < 8; ++r) acc[r] = fmaf(xs[r][i], w, acc[r]);
    }
    #pragma unroll
    for (int r = 0; r < 8; ++r) hs[r][t] = fmaxf(acc[r], 0.f);
    __syncthreads();

    if (t < 64) {
        int r = t >> 3, kk = t & 7;
        float s = b2[kk];
        for (int j = 0; j < DIM; ++j) s = fmaf(hs[r][j], W2[j * K + kk], s);
        int row = row0 + r;
        if (row < n_vars) logits[(size_t)row * K + kk] = s;
    }
}

// ---------------- Pass 0: per-block bucket histogram (LDS only) --------------
__global__ __launch_bounds__(256) void count_kernel(
    const int* __restrict__ ci, unsigned* __restrict__ hist,
    int n_edges, int nb, int tile)
{
    __shared__ unsigned hl[NBMAX];
    const int t = threadIdx.x, b = blockIdx.x;
    for (int i = t; i < nb; i += 256) hl[i] = 0u;
    __syncthreads();
    const int e0 = b * tile, e1 = min(e0 + tile, n_edges);
    for (int e = e0 + t; e < e1; e += 256)
        atomicAdd(&hl[(unsigned)ci[e] >> CSHIFT], 1u);
    __syncthreads();
    for (int i = t; i < nb; i += 256) hist[(size_t)i * SBLK + b] = hl[i];
}

// ---------------- Pass 0b: exclusive scan of each bucket row over blocks -----
__global__ __launch_bounds__(256) void scan1_kernel(
    unsigned* __restrict__ hist, unsigned* __restrict__ btotal)
{
    const int t = threadIdx.x;
    const size_t base = (size_t)blockIdx.x * SBLK + t * 4;
    uint4 v = *(const uint4*)(hist + base);
    unsigned pre0 = 0, pre1 = v.x, pre2 = v.x + v.y, pre3 = v.x + v.y + v.z;
    unsigned run = pre3 + v.w;

    __shared__ unsigned ts[256];
    ts[t] = run;
    __syncthreads();
    for (int off = 1; off < 256; off <<= 1) {
        unsigned xv = (t >= off) ? ts[t - off] : 0u;
        __syncthreads();
        ts[t] += xv;
        __syncthreads();
    }
    unsigned ex = ts[t] - run;
    uint4 o = {ex + pre0, ex + pre1, ex + pre2, ex + pre3};
    *(uint4*)(hist + base) = o;
    if (t == 255) btotal[blockIdx.x] = ts[255];
}

// ---------------- Pass 0c: scan bucket totals -> bucket_base -----------------
__global__ __launch_bounds__(256) void scan2_kernel(
    const unsigned* __restrict__ btotal, unsigned* __restrict__ bbase, int nb)
{
    const int t = threadIdx.x;
    unsigned loc[16];
    unsigned run = 0;
    #pragma unroll
    for (int it = 0; it < 16; ++it) {
        int idx = t * 16 + it;
        unsigned v = (idx < nb) ? btotal[idx] : 0u;
        loc[it] = run;
        run += v;
    }
    __shared__ unsigned ts[256];
    ts[t] = run;
    __syncthreads();
    for (int off = 1; off < 256; off <<= 1) {
        unsigned xv = (t >= off) ? ts[t - off] : 0u;
        __syncthreads();
        ts[t] += xv;
        __syncthreads();
    }
    unsigned ex = ts[t] - run;
    #pragma unroll
    for (int it = 0; it < 16; ++it) {
        int idx = t * 16 + it;
        if (idx <= nb) bbase[idx] = ex + loc[it];
    }
}

// ---------------- Pass 1: scatter packed payloads into bucket regions --------
__global__ __launch_bounds__(256) void scatter_kernel(
    const int* __restrict__ ci, const int* __restrict__ vi,
    const float* __restrict__ pol, const unsigned* __restrict__ hist,
    const unsigned* __restrict__ bbase, unsigned* __restrict__ sorted,
    int n_edges, int nb, int tile)
{
    __shared__ unsigned offs[NBMAX];
    const int t = threadIdx.x, b = blockIdx.x;
    for (int i = t; i < nb; i += 256)
        offs[i] = bbase[i] + hist[(size_t)i * SBLK + b];
    __syncthreads();
    const int e0 = b * tile, e1 = min(e0 + tile, n_edges);
    for (int e = e0 + t; e < e1; e += 256) {
        unsigned c = (unsigned)ci[e];
        unsigned v = (unsigned)vi[e];
        unsigned neg = (pol[e] < 0.f) ? 1u : 0u;
        unsigned pos = atomicAdd(&offs[c >> CSHIFT], 1u);
        sorted[pos] = (c & (CB - 1)) | (v << CSHIFT) | (neg << 29);
    }
}

// ---------------- Pass 2: per-bucket clause reduce + graph fuse --------------
__global__ __launch_bounds__(256) void bucket_kernel(
    const unsigned* __restrict__ sorted, const float* __restrict__ logits,
    const unsigned* __restrict__ bbase, const int* __restrict__ clause_batch,
    float* __restrict__ per_graph, unsigned* __restrict__ gmask,
    int n_clauses, int n_graphs)
{
    __shared__ float acc[CB * K];       // 32 KB
    __shared__ unsigned cmask[CB];      //  4 KB
    __shared__ float pg[MAXSLOT * K];   //  1 KB
    __shared__ unsigned pmask[MAXSLOT];
    __shared__ int sh_ghi;

    const int t = threadIdx.x;
    const int bkt = blockIdx.x;
    const int c_base = bkt << CSHIFT;
    const int n_cl = min(CB, n_clauses - c_base);

    for (int i = t; i < CB * K; i += 256) acc[i] = 0.f;
    for (int i = t; i < CB; i += 256) cmask[i] = 0u;
    for (int i = t; i < MAXSLOT * K; i += 256) pg[i] = 0.f;
    if (t < MAXSLOT) pmask[t] = 0xFFu;
    if (t == 0) sh_ghi = clause_batch[c_base + n_cl - 1];
    __syncthreads();

    const unsigned lo = bbase[bkt], hi = bbase[bkt + 1];
    for (unsigned e = lo + t; e < hi; e += 256) {
        unsigned pay = sorted[e];
        int cl = pay & (CB - 1);
        int v = (pay >> CSHIFT) & 0x7FFFF;
        unsigned neg = (pay >> 29) & 1u;
        const float4* lp = (const float4*)(logits + (size_t)v * K);
        float4 l0 = lp[0], l1 = lp[1];
        float l[K] = {l0.x, l0.y, l0.z, l0.w, l1.x, l1.y, l1.z, l1.w};
        float sgnv = neg ? -1.f : 1.f;
        unsigned em = 0u;
        #pragma unroll
        for (int j = 0; j < K; ++j) {
            float lit = l[j] * sgnv;
            float sp = fmaxf(lit, 0.f) + __logf(1.f + __expf(-fabsf(lit)));
            atomicAdd(&acc[cl * K + j], sp);
            em |= ((l[j] > 0.f) != (neg != 0u)) ? (1u << j) : 0u;
        }
        atomicOr(&cmask[cl], em | 0x100u);
    }
    __syncthreads();

    // fold clauses into per-graph slots (register-local accumulation)
    const int g_lo = clause_batch[c_base];
    float lacc[K];
    unsigned land = 0xFFu;
    int cur = -1;
    for (int cl = t; cl < n_cl; cl += 256) {
        int c = c_base + cl;
        int g = clause_batch[c];
        int slot = g - g_lo;
        if (slot != cur) {
            if (cur >= 0) {
                if (cur < MAXSLOT) {
                    #pragma unroll
                    for (int j = 0; j < K; ++j) atomicAdd(&pg[cur * K + j], lacc[j]);
                    atomicAnd(&pmask[cur], land);
                } else {
                    #pragma unroll
                    for (int j = 0; j < K; ++j) atomicAdd(&per_graph[(size_t)(g_lo + cur) * K + j], lacc[j]);
                    atomicAnd(&gmask[g_lo + cur], land);
                }
            }
            cur = slot;
            #pragma unroll
            for (int j = 0; j < K; ++j) lacc[j] = 0.f;
            land = 0xFFu;
        }
        unsigned m = cmask[cl];
        unsigned em8 = (m & 0x100u) ? (m & 0xFFu) : 0u;
        land &= em8;
        #pragma unroll
        for (int j = 0; j < K; ++j) {
            float s = acc[cl * K + j];
            float cv = __expf(-s);
            lacc[j] += cv * (-__logf(1.f - cv + EPS));
        }
    }
    if (cur >= 0) {
        if (cur < MAXSLOT) {
            #pragma unroll
            for (int j = 0; j < K; ++j) atomicAdd(&pg[cur * K + j], lacc[j]);
            atomicAnd(&pmask[cur], land);
        } else {
            #pragma unroll
            for (int j = 0; j < K; ++j) atomicAdd(&per_graph[(size_t)(g_lo + cur) * K + j], lacc[j]);
            atomicAnd(&gmask[g_lo + cur], land);
        }
    }
    __syncthreads();

    const int nslots = min(sh_ghi - g_lo + 1, MAXSLOT);
    if (t < nslots * K) {
        int s = t >> 3, j = t & 7;
        atomicAdd(&per_graph[(size_t)(g_lo + s) * K + j], pg[s * K + j]);
    }
    if (t < nslots) atomicAnd(&gmask[g_lo + t], pmask[t]);
}

// ---------------- Final: per-graph sqrt, sort-8, cost dot, solved ------------
__global__ __launch_bounds__(256) void final_kernel(
    const float* __restrict__ per_graph, const unsigned* __restrict__ gmask,
    int n_graphs, float* __restrict__ out)
{
    const int t = threadIdx.x;
    float dot = 0.f;
    if (t < n_graphs) {
        float v[K];
        #pragma unroll
        for (int j = 0; j < K; ++j)
            v[j] = sqrtf(per_graph[(size_t)t * K + j] + SQRT_EPS) - sqrtf(SQRT_EPS);
        #pragma unroll
        for (int i = 1; i < K; ++i) {
            float key = v[i];
            int j = i - 1;
            while (j >= 0 && v[j] < key) { v[j + 1] = v[j]; --j; }
            v[j + 1] = key;
        }
        #pragma unroll
        for (int i = 0; i < K; ++i)
            dot = fmaf(v[i], (float)((i + 1) * (i + 1)), dot);
        out[1 + t] = (gmask[t] & 0xFFu) ? 1.f : 0.f;
    }
    __shared__ float red[256];
    red[t] = dot;
    __syncthreads();
    for (int s = 128; s >= 1; s >>= 1) {
        if (t < s) red[t] += red[t + s];
        __syncthreads();
    }
    if (t == 0) out[0] = red[0] * (1.f / 204.f);
}

// ---------------------------------------------------------------------------
extern "C" void kernel_launch(void* const* d_in, const int* in_sizes, int n_in,
                              void* d_out, int out_size, void* d_ws, size_t ws_size,
                              hipStream_t stream) {
    const float* x   = (const float*)d_in[0];
    const float* pol = (const float*)d_in[1];
    const int* vi    = (const int*)d_in[2];
    const int* ci    = (const int*)d_in[3];
    const int* cb    = (const int*)d_in[4];
    const float* W1  = (const float*)d_in[5];
    const float* b1  = (const float*)d_in[6];
    const float* W2  = (const float*)d_in[7];
    const float* b2  = (const float*)d_in[8];

    const int n_vars    = in_sizes[0] / DIM;
    const int n_edges   = in_sizes[1];
    const int n_clauses = in_sizes[4];
    const int n_graphs  = out_size - 1;
    const int nb        = (n_clauses + CB - 1) / CB;
    const int tile      = (n_edges + SBLK - 1) / SBLK;

    // ---- workspace layout (256B aligned regions) ----
    char* ws = (char*)d_ws;
    size_t off = 0;
    auto alloc = [&](size_t bytes) { char* p = ws + off; off += (bytes + 255) & ~(size_t)255; return p; };
    float*    logits   = (float*)alloc((size_t)n_vars * K * 4);        // 16 MB
    unsigned* sorted   = (unsigned*)alloc((size_t)n_edges * 4);        // 24 MB
    unsigned* hist     = (unsigned*)alloc((size_t)NBMAX * SBLK * 4);   //  8 MB
    unsigned* btotal   = (unsigned*)alloc((size_t)NBMAX * 4);
    unsigned* bbase    = (unsigned*)alloc((size_t)(NBMAX + 1) * 4);
    float*    per_graph= (float*)alloc((size_t)n_graphs * K * 4);
    unsigned* gmask    = (unsigned*)alloc((size_t)n_graphs * 4);

    hipMemsetAsync(per_graph, 0, (size_t)n_graphs * K * 4, stream);
    hipMemsetAsync(gmask, 0xFF, (size_t)n_graphs * 4, stream);

    count_kernel<<<SBLK, 256, 0, stream>>>(ci, hist, n_edges, nb, tile);
    scan1_kernel<<<nb, 256, 0, stream>>>(hist, btotal);
    scan2_kernel<<<1, 256, 0, stream>>>(btotal, bbase, nb);
    scatter_kernel<<<SBLK, 256, 0, stream>>>(ci, vi, pol, hist, bbase, sorted,
                                             n_edges, nb, tile);
    mlp_kernel<<<(n_vars + 7) / 8, 128, 0, stream>>>(x, W1, b1, W2, b2, logits, n_vars);
    bucket_kernel<<<nb, 256, 0, stream>>>(sorted, logits, bbase, cb,
                                          per_graph, gmask, n_clauses, n_graphs);
    final_kernel<<<1, 256, 0, stream>>>(per_graph, gmask, n_graphs, (float*)d_out);
}

// Round 3
// 594.733 us; speedup vs baseline: 5.3297x; 1.4528x over previous
//
#include <hip/hip_runtime.h>
#include <hip/hip_bf16.h>

#define DIM 128
#define K 8
#define EPS 1e-8f
#define SQRT_EPS 1e-6f

#define CB 1024          // clauses per bucket
#define CSHIFT 10
#define NBMAX 2048       // max buckets (n_clauses/CB = 1954 here)
#define SBLK 1024        // partition blocks
#define MAXSLOT 32       // graph slots per bucket

typedef __attribute__((ext_vector_type(8))) short bf16x8;
typedef __attribute__((ext_vector_type(4))) float f32x4;

__device__ inline short bfc(float f) {
    union { __hip_bfloat16 h; short s; } u;
    u.h = __float2bfloat16(f);
    return u.s;
}

#define LDW 136  // padded LDS row (bf16 elements): 272B -> 2-way max bank aliasing

// ---------------- MLP via MFMA: logits = relu(x@W1+b1)@W2+b2 -----------------
__global__ __launch_bounds__(256) void mlp_kernel(
    const float* __restrict__ x, const float* __restrict__ W1,
    const float* __restrict__ b1, const float* __restrict__ W2,
    const float* __restrict__ b2, float* __restrict__ logits, int n_vars)
{
    __shared__ __align__(16) short w1t[DIM][LDW];     // W1^T as bf16 (34.8 KB)
    __shared__ __align__(16) short w2t[16][LDW];      // W2^T (cols 8..15 zero)
    __shared__ __align__(16) short hlds[4][16][LDW];  // per-wave H row-tile

    const int t = threadIdx.x;
    const int wave = t >> 6, lane = t & 63;
    const int lr = lane & 15, lg = lane >> 4;

    // stage W1^T, W2^T into LDS (bf16)
    for (int i = t; i < DIM * DIM; i += 256) {
        int r = i >> 7, c = i & 127;          // W1[r][c]
        w1t[c][r] = bfc(W1[i]);
    }
    for (int i = t; i < 16 * DIM; i += 256) {
        int c = i >> 7, j = i & 127;          // w2t[c][j] = W2[j][c]
        w2t[c][j] = (c < 8) ? bfc(W2[j * 8 + c]) : (short)0;
    }
    __syncthreads();

    const int rbase = blockIdx.x * 128 + wave * 32;

    // A-fragments of x for both row-tiles (bf16 in-register conversion)
    bf16x8 a[2][4];
    #pragma unroll
    for (int rt = 0; rt < 2; ++rt) {
        int row = rbase + rt * 16 + lr;
        bool ok = row < n_vars;
        const float* xp = x + (size_t)row * DIM + lg * 8;
        #pragma unroll
        for (int kt = 0; kt < 4; ++kt) {
            bf16x8 av = {0,0,0,0,0,0,0,0};
            if (ok) {
                float4 f0 = *(const float4*)(xp + kt * 32);
                float4 f1 = *(const float4*)(xp + kt * 32 + 4);
                av[0]=bfc(f0.x); av[1]=bfc(f0.y); av[2]=bfc(f0.z); av[3]=bfc(f0.w);
                av[4]=bfc(f1.x); av[5]=bfc(f1.y); av[6]=bfc(f1.z); av[7]=bfc(f1.w);
            }
            a[rt][kt] = av;
        }
    }

    // W2 B-fragments (invariant across row-tiles)
    bf16x8 bb[4];
    #pragma unroll
    for (int kt = 0; kt < 4; ++kt)
        bb[kt] = *(const bf16x8*)&w2t[lr][kt * 32 + lg * 8];
    float b2v = (lr < 8) ? b2[lr] : 0.f;

    #pragma unroll
    for (int rt = 0; rt < 2; ++rt) {
        // ---- layer 1: 8 col-tiles of 16, K=128 ----
        #pragma unroll
        for (int n = 0; n < 8; ++n) {
            f32x4 acc = {0.f, 0.f, 0.f, 0.f};
            #pragma unroll
            for (int kt = 0; kt < 4; ++kt) {
                bf16x8 bf = *(const bf16x8*)&w1t[n * 16 + lr][kt * 32 + lg * 8];
                acc = __builtin_amdgcn_mfma_f32_16x16x32_bf16(a[rt][kt], bf, acc, 0, 0, 0);
            }
            float bcol = b1[n * 16 + lr];
            #pragma unroll
            for (int r = 0; r < 4; ++r) {
                float h = fmaxf(acc[r] + bcol, 0.f);
                hlds[wave][lg * 4 + r][n * 16 + lr] = bfc(h);   // C layout: row=(l>>4)*4+r, col=l&15
            }
        }
        // ---- layer 2: K=128, N=16 (8 valid) ----
        f32x4 acc2 = {0.f, 0.f, 0.f, 0.f};
        #pragma unroll
        for (int kt = 0; kt < 4; ++kt) {
            bf16x8 af = *(const bf16x8*)&hlds[wave][lr][kt * 32 + lg * 8];
            acc2 = __builtin_amdgcn_mfma_f32_16x16x32_bf16(af, bb[kt], acc2, 0, 0, 0);
        }
        if (lr < 8) {
            #pragma unroll
            for (int r = 0; r < 4; ++r) {
                int row = rbase + rt * 16 + lg * 4 + r;
                if (row < n_vars)
                    logits[(size_t)row * K + lr] = acc2[r] + b2v;
            }
        }
    }
}

// ---------------- Pass 0: per-block bucket histogram (LDS only) --------------
__global__ __launch_bounds__(256) void count_kernel(
    const int* __restrict__ ci, unsigned* __restrict__ hist,
    int n_edges, int nb, int tile)
{
    __shared__ unsigned hl[NBMAX];
    const int t = threadIdx.x, b = blockIdx.x;
    for (int i = t; i < nb; i += 256) hl[i] = 0u;
    __syncthreads();
    const int e0 = b * tile, e1 = min(e0 + tile, n_edges);
    for (int e = e0 + t; e < e1; e += 256)
        atomicAdd(&hl[(unsigned)ci[e] >> CSHIFT], 1u);
    __syncthreads();
    for (int i = t; i < nb; i += 256) hist[(size_t)i * SBLK + b] = hl[i];
}

// ---------------- Pass 0b: exclusive scan of each bucket row over blocks -----
__global__ __launch_bounds__(256) void scan1_kernel(
    unsigned* __restrict__ hist, unsigned* __restrict__ btotal)
{
    const int t = threadIdx.x;
    const size_t base = (size_t)blockIdx.x * SBLK + t * 4;
    uint4 v = *(const uint4*)(hist + base);
    unsigned pre0 = 0, pre1 = v.x, pre2 = v.x + v.y, pre3 = v.x + v.y + v.z;
    unsigned run = pre3 + v.w;

    __shared__ unsigned ts[256];
    ts[t] = run;
    __syncthreads();
    for (int off = 1; off < 256; off <<= 1) {
        unsigned xv = (t >= off) ? ts[t - off] : 0u;
        __syncthreads();
        ts[t] += xv;
        __syncthreads();
    }
    unsigned ex = ts[t] - run;
    uint4 o = {ex + pre0, ex + pre1, ex + pre2, ex + pre3};
    *(uint4*)(hist + base) = o;
    if (t == 255) btotal[blockIdx.x] = ts[255];
}

// ---------------- Pass 0c: scan bucket totals -> bucket_base -----------------
__global__ __launch_bounds__(256) void scan2_kernel(
    const unsigned* __restrict__ btotal, unsigned* __restrict__ bbase, int nb)
{
    const int t = threadIdx.x;
    unsigned loc[16];
    unsigned run = 0;
    #pragma unroll
    for (int it = 0; it < 16; ++it) {
        int idx = t * 16 + it;
        unsigned v = (idx < nb) ? btotal[idx] : 0u;
        loc[it] = run;
        run += v;
    }
    __shared__ unsigned ts[256];
    ts[t] = run;
    __syncthreads();
    for (int off = 1; off < 256; off <<= 1) {
        unsigned xv = (t >= off) ? ts[t - off] : 0u;
        __syncthreads();
        ts[t] += xv;
        __syncthreads();
    }
    unsigned ex = ts[t] - run;
    #pragma unroll
    for (int it = 0; it < 16; ++it) {
        int idx = t * 16 + it;
        if (idx <= nb) bbase[idx] = ex + loc[it];
    }
}

// ---------------- Pass 1: scatter packed payloads into bucket regions --------
__global__ __launch_bounds__(256) void scatter_kernel(
    const int* __restrict__ ci, const int* __restrict__ vi,
    const float* __restrict__ pol, const unsigned* __restrict__ hist,
    const unsigned* __restrict__ bbase, unsigned* __restrict__ sorted,
    int n_edges, int nb, int tile)
{
    __shared__ unsigned offs[NBMAX];
    const int t = threadIdx.x, b = blockIdx.x;
    for (int i = t; i < nb; i += 256)
        offs[i] = bbase[i] + hist[(size_t)i * SBLK + b];
    __syncthreads();
    const int e0 = b * tile, e1 = min(e0 + tile, n_edges);
    for (int e = e0 + t; e < e1; e += 256) {
        unsigned c = (unsigned)ci[e];
        unsigned v = (unsigned)vi[e];
        unsigned neg = (pol[e] < 0.f) ? 1u : 0u;
        unsigned pos = atomicAdd(&offs[c >> CSHIFT], 1u);
        sorted[pos] = (c & (CB - 1)) | (v << CSHIFT) | (neg << 29);
    }
}

// ---------------- Pass 2: per-bucket clause reduce + graph fuse --------------
__global__ __launch_bounds__(256) void bucket_kernel(
    const unsigned* __restrict__ sorted, const float* __restrict__ logits,
    const unsigned* __restrict__ bbase, const int* __restrict__ clause_batch,
    float* __restrict__ per_graph, unsigned* __restrict__ gmask,
    int n_clauses, int n_graphs)
{
    __shared__ float acc[CB * K];       // 32 KB
    __shared__ unsigned cmask[CB];      //  4 KB
    __shared__ float pg[MAXSLOT * K];   //  1 KB
    __shared__ unsigned pmask[MAXSLOT];
    __shared__ int sh_ghi;

    const int t = threadIdx.x;
    const int bkt = blockIdx.x;
    const int c_base = bkt << CSHIFT;
    const int n_cl = min(CB, n_clauses - c_base);

    for (int i = t; i < CB * K; i += 256) acc[i] = 0.f;
    for (int i = t; i < CB; i += 256) cmask[i] = 0u;
    for (int i = t; i < MAXSLOT * K; i += 256) pg[i] = 0.f;
    if (t < MAXSLOT) pmask[t] = 0xFFu;
    if (t == 0) sh_ghi = clause_batch[c_base + n_cl - 1];
    __syncthreads();

    const unsigned lo = bbase[bkt], hi = bbase[bkt + 1];
    for (unsigned e = lo + t; e < hi; e += 256) {
        unsigned pay = sorted[e];
        int cl = pay & (CB - 1);
        int v = (pay >> CSHIFT) & 0x7FFFF;
        unsigned neg = (pay >> 29) & 1u;
        const float4* lp = (const float4*)(logits + (size_t)v * K);
        float4 l0 = lp[0], l1 = lp[1];
        float l[K] = {l0.x, l0.y, l0.z, l0.w, l1.x, l1.y, l1.z, l1.w};
        float sgnv = neg ? -1.f : 1.f;
        unsigned em = 0u;
        #pragma unroll
        for (int j = 0; j < K; ++j) {
            float lit = l[j] * sgnv;
            float sp = fmaxf(lit, 0.f) + __logf(1.f + __expf(-fabsf(lit)));
            atomicAdd(&acc[cl * K + j], sp);
            em |= ((l[j] > 0.f) != (neg != 0u)) ? (1u << j) : 0u;
        }
        atomicOr(&cmask[cl], em | 0x100u);
    }
    __syncthreads();

    // fold clauses into per-graph slots (register-local accumulation)
    const int g_lo = clause_batch[c_base];
    float lacc[K];
    unsigned land = 0xFFu;
    int cur = -1;
    for (int cl = t; cl < n_cl; cl += 256) {
        int c = c_base + cl;
        int g = clause_batch[c];
        int slot = g - g_lo;
        if (slot != cur) {
            if (cur >= 0) {
                if (cur < MAXSLOT) {
                    #pragma unroll
                    for (int j = 0; j < K; ++j) atomicAdd(&pg[cur * K + j], lacc[j]);
                    atomicAnd(&pmask[cur], land);
                } else {
                    #pragma unroll
                    for (int j = 0; j < K; ++j) atomicAdd(&per_graph[(size_t)(g_lo + cur) * K + j], lacc[j]);
                    atomicAnd(&gmask[g_lo + cur], land);
                }
            }
            cur = slot;
            #pragma unroll
            for (int j = 0; j < K; ++j) lacc[j] = 0.f;
            land = 0xFFu;
        }
        unsigned m = cmask[cl];
        unsigned em8 = (m & 0x100u) ? (m & 0xFFu) : 0u;
        land &= em8;
        #pragma unroll
        for (int j = 0; j < K; ++j) {
            float s = acc[cl * K + j];
            float cv = __expf(-s);
            lacc[j] += cv * (-__logf(1.f - cv + EPS));
        }
    }
    if (cur >= 0) {
        if (cur < MAXSLOT) {
            #pragma unroll
            for (int j = 0; j < K; ++j) atomicAdd(&pg[cur * K + j], lacc[j]);
            atomicAnd(&pmask[cur], land);
        } else {
            #pragma unroll
            for (int j = 0; j < K; ++j) atomicAdd(&per_graph[(size_t)(g_lo + cur) * K + j], lacc[j]);
            atomicAnd(&gmask[g_lo + cur], land);
        }
    }
    __syncthreads();

    const int nslots = min(sh_ghi - g_lo + 1, MAXSLOT);
    if (t < nslots * K) {
        int s = t >> 3, j = t & 7;
        atomicAdd(&per_graph[(size_t)(g_lo + s) * K + j], pg[s * K + j]);
    }
    if (t < nslots) atomicAnd(&gmask[g_lo + t], pmask[t]);
}

// ---------------- Final: per-graph sqrt, sort-8, cost dot, solved ------------
__global__ __launch_bounds__(256) void final_kernel(
    const float* __restrict__ per_graph, const unsigned* __restrict__ gmask,
    int n_graphs, float* __restrict__ out)
{
    const int t = threadIdx.x;
    float dot = 0.f;
    if (t < n_graphs) {
        float v[K];
        #pragma unroll
        for (int j = 0; j < K; ++j)
            v[j] = sqrtf(per_graph[(size_t)t * K + j] + SQRT_EPS) - sqrtf(SQRT_EPS);
        #pragma unroll
        for (int i = 1; i < K; ++i) {
            float key = v[i];
            int j = i - 1;
            while (j >= 0 && v[j] < key) { v[j + 1] = v[j]; --j; }
            v[j + 1] = key;
        }
        #pragma unroll
        for (int i = 0; i < K; ++i)
            dot = fmaf(v[i], (float)((i + 1) * (i + 1)), dot);
        out[1 + t] = (gmask[t] & 0xFFu) ? 1.f : 0.f;
    }
    __shared__ float red[256];
    red[t] = dot;
    __syncthreads();
    for (int s = 128; s >= 1; s >>= 1) {
        if (t < s) red[t] += red[t + s];
        __syncthreads();
    }
    if (t == 0) out[0] = red[0] * (1.f / 204.f);
}

// ---------------------------------------------------------------------------
extern "C" void kernel_launch(void* const* d_in, const int* in_sizes, int n_in,
                              void* d_out, int out_size, void* d_ws, size_t ws_size,
                              hipStream_t stream) {
    const float* x   = (const float*)d_in[0];
    const float* pol = (const float*)d_in[1];
    const int* vi    = (const int*)d_in[2];
    const int* ci    = (const int*)d_in[3];
    const int* cb    = (const int*)d_in[4];
    const float* W1  = (const float*)d_in[5];
    const float* b1  = (const float*)d_in[6];
    const float* W2  = (const float*)d_in[7];
    const float* b2  = (const float*)d_in[8];

    const int n_vars    = in_sizes[0] / DIM;
    const int n_edges   = in_sizes[1];
    const int n_clauses = in_sizes[4];
    const int n_graphs  = out_size - 1;
    const int nb        = (n_clauses + CB - 1) / CB;
    const int tile      = (n_edges + SBLK - 1) / SBLK;

    // ---- workspace layout (256B aligned regions) ----
    char* ws = (char*)d_ws;
    size_t off = 0;
    auto alloc = [&](size_t bytes) { char* p = ws + off; off += (bytes + 255) & ~(size_t)255; return p; };
    float*    logits   = (float*)alloc((size_t)n_vars * K * 4);        // 16 MB
    unsigned* sorted   = (unsigned*)alloc((size_t)n_edges * 4);        // 24 MB
    unsigned* hist     = (unsigned*)alloc((size_t)NBMAX * SBLK * 4);   //  8 MB
    unsigned* btotal   = (unsigned*)alloc((size_t)NBMAX * 4);
    unsigned* bbase    = (unsigned*)alloc((size_t)(NBMAX + 1) * 4);
    float*    per_graph= (float*)alloc((size_t)n_graphs * K * 4);
    unsigned* gmask    = (unsigned*)alloc((size_t)n_graphs * 4);

    hipMemsetAsync(per_graph, 0, (size_t)n_graphs * K * 4, stream);
    hipMemsetAsync(gmask, 0xFF, (size_t)n_graphs * 4, stream);

    count_kernel<<<SBLK, 256, 0, stream>>>(ci, hist, n_edges, nb, tile);
    scan1_kernel<<<nb, 256, 0, stream>>>(hist, btotal);
    scan2_kernel<<<1, 256, 0, stream>>>(btotal, bbase, nb);
    scatter_kernel<<<SBLK, 256, 0, stream>>>(ci, vi, pol, hist, bbase, sorted,
                                             n_edges, nb, tile);
    mlp_kernel<<<(n_vars + 127) / 128, 256, 0, stream>>>(x, W1, b1, W2, b2, logits, n_vars);
    bucket_kernel<<<nb, 256, 0, stream>>>(sorted, logits, bbase, cb,
                                          per_graph, gmask, n_clauses, n_graphs);
    final_kernel<<<1, 256, 0, stream>>>(per_graph, gmask, n_graphs, (float*)d_out);
}